// Round 19
// baseline (377.175 us; speedup 1.0000x reference)
//
#include <hip/hip_runtime.h>

#define HDIM 64
#define CAP_M 96
#define CAP_U 32
#define OVF_MAX 65536
#define NBIN 512
#define NBLK 2048

typedef __attribute__((ext_vector_type(8))) short bf16x8;   // 8 bf16 (4 VGPRs)
typedef __attribute__((ext_vector_type(4))) float f32x4;    // 4 fp32

// ---------------- bf16 helpers ----------------
__device__ __forceinline__ float bf2f(unsigned short u) {
  unsigned int x = ((unsigned int)u) << 16;
  return __uint_as_float(x);
}
__device__ __forceinline__ unsigned short f2bf(float f) {
  unsigned int x = __float_as_uint(f);
  unsigned int r = (x + 0x7FFFu + ((x >> 16) & 1u)) >> 16;  // RNE
  return (unsigned short)r;
}

// bin-local base: lo(b) = ceil(b*Nd/NBIN); bin(k) = floor(k*NBIN/Nd)
__device__ __forceinline__ int bin_lo(int b, int Nd) {
  return (int)(((long long)b * Nd + NBIN - 1) >> 9);
}

// ---------------- init: zero meta + bf16 table copies (r13 proven) ----------------
__global__ __launch_bounds__(256) void k_init(int* __restrict__ meta, int nmeta,
                                              const float* __restrict__ ut,
                                              unsigned short* __restrict__ ub, int n8u,
                                              const float* __restrict__ mt,
                                              unsigned short* __restrict__ mb, int n8m) {
  int bid = blockIdx.x;
  if (bid < 512) {
    int i = bid * 256 + threadIdx.x;
    for (int j = i; j < nmeta; j += 512 * 256) meta[j] = 0;
  } else if (bid < 512 + 2048) {
    int i = (bid - 512) * 256 + threadIdx.x;
    for (int j = i; j < n8u; j += 2048 * 256) {
      const float4* p = (const float4*)(ut + (size_t)j * 8);
      float4 a = p[0], b = p[1];
      uint4 o;
      o.x = (unsigned int)f2bf(a.x) | ((unsigned int)f2bf(a.y) << 16);
      o.y = (unsigned int)f2bf(a.z) | ((unsigned int)f2bf(a.w) << 16);
      o.z = (unsigned int)f2bf(b.x) | ((unsigned int)f2bf(b.y) << 16);
      o.w = (unsigned int)f2bf(b.z) | ((unsigned int)f2bf(b.w) << 16);
      *(uint4*)(ub + (size_t)j * 8) = o;
    }
  } else {
    int i = (bid - 512 - 2048) * 256 + threadIdx.x;
    for (int j = i; j < n8m; j += 512 * 256) {
      const float4* p = (const float4*)(mt + (size_t)j * 8);
      float4 a = p[0], b = p[1];
      uint4 o;
      o.x = (unsigned int)f2bf(a.x) | ((unsigned int)f2bf(a.y) << 16);
      o.y = (unsigned int)f2bf(a.z) | ((unsigned int)f2bf(a.w) << 16);
      o.z = (unsigned int)f2bf(b.x) | ((unsigned int)f2bf(b.y) << 16);
      o.w = (unsigned int)f2bf(b.z) | ((unsigned int)f2bf(b.w) << 16);
      *(uint4*)(mb + (size_t)j * 8) = o;
    }
  }
}

// ---------------- binned CSR build (no global atomics on hot path) ----------------
// Phase 1 (fused): per-block 512-bin histograms for BOTH directions.
// NBLK blocks for 4x occupancy (r18 lesson: build is latency-bound, not byte-bound).
__global__ __launch_bounds__(256) void k_hist2(const int* __restrict__ srcU,
                                               const int* __restrict__ dstM,
                                               int E, int NMd, int NUd,
                                               int* __restrict__ ghM,
                                               int* __restrict__ ghU) {
  __shared__ int hM[NBIN];
  __shared__ int hU[NBIN];
  int t = threadIdx.x;
  hM[t] = 0; hM[t + 256] = 0;
  hU[t] = 0; hU[t + 256] = 0;
  __syncthreads();
  int e4 = (E + 3) >> 2;
  int c4 = (e4 + NBLK - 1) / NBLK;
  int clen = c4 << 2;
  int s = blockIdx.x * clen;
  int epos = s + clen; if (epos > E) epos = E;
  for (int i = s + 4 * t; i < epos; i += 1024) {
    int n = epos - i; if (n > 4) n = 4;
    if (n == 4) {
      int4 d4 = *(const int4*)&dstM[i];
      int4 s4 = *(const int4*)&srcU[i];
      atomicAdd(&hM[(int)((long long)d4.x * NBIN / NMd)], 1);
      atomicAdd(&hM[(int)((long long)d4.y * NBIN / NMd)], 1);
      atomicAdd(&hM[(int)((long long)d4.z * NBIN / NMd)], 1);
      atomicAdd(&hM[(int)((long long)d4.w * NBIN / NMd)], 1);
      atomicAdd(&hU[(int)((long long)s4.x * NBIN / NUd)], 1);
      atomicAdd(&hU[(int)((long long)s4.y * NBIN / NUd)], 1);
      atomicAdd(&hU[(int)((long long)s4.z * NBIN / NUd)], 1);
      atomicAdd(&hU[(int)((long long)s4.w * NBIN / NUd)], 1);
    } else {
      for (int j = 0; j < n; ++j) {
        atomicAdd(&hM[(int)((long long)dstM[i + j] * NBIN / NMd)], 1);
        atomicAdd(&hU[(int)((long long)srcU[i + j] * NBIN / NUd)], 1);
      }
    }
  }
  __syncthreads();
  ghM[(size_t)t * NBLK + blockIdx.x] = hM[t];
  ghM[(size_t)(t + 256) * NBLK + blockIdx.x] = hM[t + 256];
  ghU[(size_t)t * NBLK + blockIdx.x] = hU[t];
  ghU[(size_t)(t + 256) * NBLK + blockIdx.x] = hU[t + 256];
}

// scan kernels: chunk 1024/block; up to 1024 partials via k_scan_part4.
__global__ void k_block_sum(const int* __restrict__ in, int* __restrict__ part, int n) {
  __shared__ int s[256];
  int b = blockIdx.x, t = threadIdx.x;
  int base = b * 1024;
  int v = 0;
  for (int i = t; i < 1024; i += 256) {
    int idx = base + i;
    if (idx < n) v += in[idx];
  }
  s[t] = v;
  __syncthreads();
  for (int o = 128; o > 0; o >>= 1) {
    if (t < o) s[t] += s[t + o];
    __syncthreads();
  }
  if (t == 0) part[b] = s[0];
}

// exclusive scan of up to 1024 partials (4/thread)
__global__ void k_scan_part4(int* __restrict__ part, int nb) {
  __shared__ int s[256];
  int t = threadIdx.x;
  int v[4];
  int sum = 0;
#pragma unroll
  for (int i = 0; i < 4; ++i) {
    int idx = t * 4 + i;
    v[i] = (idx < nb) ? part[idx] : 0;
    sum += v[i];
  }
  s[t] = sum;
  __syncthreads();
  for (int o = 1; o < 256; o <<= 1) {
    int u = (t >= o) ? s[t - o] : 0;
    __syncthreads();
    s[t] += u;
    __syncthreads();
  }
  int excl = s[t] - sum;
#pragma unroll
  for (int i = 0; i < 4; ++i) {
    int idx = t * 4 + i;
    if (idx < nb) { int tmp = v[i]; part[idx] = excl; excl += tmp; }
  }
}

// in-place-safe final scan (each thread reads its 4 before writing)
__global__ void k_scan_final(const int* __restrict__ in, const int* __restrict__ part,
                             int* __restrict__ out, int n) {
  __shared__ int s[256];
  int b = blockIdx.x, t = threadIdx.x;
  int base = b * 1024 + t * 4;
  int a[4];
#pragma unroll
  for (int i = 0; i < 4; i++) a[i] = (base + i < n) ? in[base + i] : 0;
  int tsum = a[0] + a[1] + a[2] + a[3];
  s[t] = tsum;
  __syncthreads();
  for (int o = 1; o < 256; o <<= 1) {
    int u = (t >= o) ? s[t - o] : 0;
    __syncthreads();
    s[t] += u;
    __syncthreads();
  }
  int excl = s[t] - tsum + part[b];
#pragma unroll
  for (int i = 0; i < 4; i++) {
    if (base + i < n) out[base + i] = excl;
    excl += a[i];
  }
}

// Phase 2 (fused): scatter BOTH directions, 4-byte packed records:
// pk = (bin_local_key << 18) | value.  NBLK blocks for occupancy.
__global__ __launch_bounds__(256) void k_scatter2(const int* __restrict__ srcU,
                                                  const int* __restrict__ dstM,
                                                  int E, int NMd, int NUd,
                                                  const int* __restrict__ offsM,
                                                  const int* __restrict__ offsU,
                                                  unsigned int* __restrict__ binnedM,
                                                  unsigned int* __restrict__ binnedU) {
  __shared__ int lcM[NBIN];
  __shared__ int lcU[NBIN];
  int t = threadIdx.x;
  lcM[t] = offsM[(size_t)t * NBLK + blockIdx.x];
  lcM[t + 256] = offsM[(size_t)(t + 256) * NBLK + blockIdx.x];
  lcU[t] = offsU[(size_t)t * NBLK + blockIdx.x];
  lcU[t + 256] = offsU[(size_t)(t + 256) * NBLK + blockIdx.x];
  __syncthreads();
  int e4 = (E + 3) >> 2;
  int c4 = (e4 + NBLK - 1) / NBLK;
  int clen = c4 << 2;
  int s = blockIdx.x * clen;
  int epos = s + clen; if (epos > E) epos = E;
  for (int i = s + 4 * t; i < epos; i += 1024) {
    int n = epos - i; if (n > 4) n = 4;
    if (n == 4) {
      int4 d4 = *(const int4*)&dstM[i];
      int4 s4 = *(const int4*)&srcU[i];
#pragma unroll
      for (int k = 0; k < 4; ++k) {
        int dd = (k == 0) ? d4.x : (k == 1) ? d4.y : (k == 2) ? d4.z : d4.w;
        int ss = (k == 0) ? s4.x : (k == 1) ? s4.y : (k == 2) ? s4.z : s4.w;
        int bm = (int)((long long)dd * NBIN / NMd);
        int pm = atomicAdd(&lcM[bm], 1);
        binnedM[pm] = ((unsigned int)(dd - bin_lo(bm, NMd)) << 18) | (unsigned int)ss;
        int bu = (int)((long long)ss * NBIN / NUd);
        int pu = atomicAdd(&lcU[bu], 1);
        binnedU[pu] = ((unsigned int)(ss - bin_lo(bu, NUd)) << 18) | (unsigned int)dd;
      }
    } else {
      for (int j = 0; j < n; ++j) {
        int dd = dstM[i + j], ss = srcU[i + j];
        int bm = (int)((long long)dd * NBIN / NMd);
        int pm = atomicAdd(&lcM[bm], 1);
        binnedM[pm] = ((unsigned int)(dd - bin_lo(bm, NMd)) << 18) | (unsigned int)ss;
        int bu = (int)((long long)ss * NBIN / NUd);
        int pu = atomicAdd(&lcU[bu], 1);
        binnedU[pu] = ((unsigned int)(ss - bin_lo(bu, NUd)) << 18) | (unsigned int)dd;
      }
    }
  }
}

// Phase 3: one block per bin; cursors in LDS; decode packed records.
template <typename IT>
__global__ __launch_bounds__(256) void k_fillbin(const unsigned int* __restrict__ binned,
                                                 const int* __restrict__ offs,
                                                 int E, int Nd, int cap,
                                                 IT* __restrict__ bkt,
                                                 int* __restrict__ cur,
                                                 int* __restrict__ ovf_cnt,
                                                 int* __restrict__ ovf) {
  __shared__ int lcur[400];
  int b = blockIdx.x;
  int t = threadIdx.x;
  int lo = bin_lo(b, Nd);
  int hi = bin_lo(b + 1, Nd);
  if (b == NBIN - 1) hi = Nd;
  int width = hi - lo;
  for (int i = t; i < width; i += 256) lcur[i] = 0;
  __syncthreads();
  int start = offs[(size_t)b * NBLK];
  int end = (b == NBIN - 1) ? E : offs[(size_t)(b + 1) * NBLK];
  for (int i = start + t; i < end; i += 256) {
    unsigned int p = binned[i];
    int li = (int)(p >> 18);
    int val = (int)(p & 0x3FFFFu);
    int pos = atomicAdd(&lcur[li], 1);
    if (pos < cap) bkt[(size_t)(lo + li) * cap + pos] = (IT)val;
    else { int q = atomicAdd(ovf_cnt, 1); if (q < OVF_MAX) { ovf[2 * q] = lo + li; ovf[2 * q + 1] = val; } }
  }
  __syncthreads();
  for (int i = t; i < width; i += 256) cur[lo + i] = lcur[i];
}

// ---------------- aggregation: 8 lanes/node, 16B uint4 loads (r13 proven) ----------------
__device__ __forceinline__ void acc8(float4& a, float4& b, uint4 w) {
  a.x += __uint_as_float(w.x << 16);
  a.y += __uint_as_float(w.x & 0xFFFF0000u);
  a.z += __uint_as_float(w.y << 16);
  a.w += __uint_as_float(w.y & 0xFFFF0000u);
  b.x += __uint_as_float(w.z << 16);
  b.y += __uint_as_float(w.z & 0xFFFF0000u);
  b.z += __uint_as_float(w.w << 16);
  b.w += __uint_as_float(w.w & 0xFFFF0000u);
}

template <typename IT>
__global__ __launch_bounds__(256) void k_agg8(const unsigned short* __restrict__ xb,
                                              const int* __restrict__ cur,
                                              const IT* __restrict__ bkt,
                                              int cap,
                                              float* __restrict__ agg,
                                              int n_dst) {
  int t = threadIdx.x;
  int q = t & 7;
  int gg = (blockIdx.x * 256 + t) >> 3;
  int stride = (gridDim.x * 256) >> 3;

  for (int node = gg; node < n_dst; node += stride) {
    int deg = cur[node];
    int nb = deg < cap ? deg : cap;
    const IT* lst = bkt + (size_t)node * cap;
    float4 a = make_float4(0.f, 0.f, 0.f, 0.f);
    float4 b = a;
    int e = 0;
    for (; e + 4 <= nb; e += 4) {
      int i0, i1, i2, i3;
      if (sizeof(IT) == 2) {
        ushort4 ia = *(const ushort4*)&lst[e];
        i0 = ia.x; i1 = ia.y; i2 = ia.z; i3 = ia.w;
      } else {
        int4 ia = *(const int4*)&lst[e];
        i0 = ia.x; i1 = ia.y; i2 = ia.z; i3 = ia.w;
      }
      uint4 w0 = *(const uint4*)&xb[(size_t)i0 * HDIM + 8 * q];
      uint4 w1 = *(const uint4*)&xb[(size_t)i1 * HDIM + 8 * q];
      uint4 w2 = *(const uint4*)&xb[(size_t)i2 * HDIM + 8 * q];
      uint4 w3 = *(const uint4*)&xb[(size_t)i3 * HDIM + 8 * q];
      acc8(a, b, w0);
      acc8(a, b, w1);
      acc8(a, b, w2);
      acc8(a, b, w3);
    }
    for (; e < nb; ++e) {
      uint4 w0 = *(const uint4*)&xb[(size_t)lst[e] * HDIM + 8 * q];
      acc8(a, b, w0);
    }
    float inv = deg > 0 ? 1.f / (float)deg : 0.f;
    a.x *= inv; a.y *= inv; a.z *= inv; a.w *= inv;
    b.x *= inv; b.y *= inv; b.z *= inv; b.w *= inv;
    *(float4*)&agg[(size_t)node * HDIM + 8 * q] = a;
    *(float4*)&agg[(size_t)node * HDIM + 8 * q + 4] = b;
  }
}

// ---------------- overflow fixup (combined; normally a no-op) ----------------
__device__ __forceinline__ void fix_body(const int* __restrict__ cnt_p,
                                         const int* __restrict__ ovf,
                                         const unsigned short* __restrict__ xb,
                                         const int* __restrict__ cur,
                                         float* __restrict__ agg,
                                         int bid, int nblk) {
  int n = *cnt_p;
  if (n > OVF_MAX) n = OVF_MAX;
  int tid = bid * 256 + threadIdx.x;
  int q = tid & 15;
  int p = tid >> 4;
  int stride = (nblk * 256) >> 4;
  for (; p < n; p += stride) {
    int d = ovf[2 * p];
    int s = ovf[2 * p + 1];
    float inv = 1.f / (float)cur[d];
    ushort4 v = *(const ushort4*)&xb[(size_t)s * HDIM + 4 * q];
    atomicAdd(&agg[(size_t)d * HDIM + 4 * q + 0], bf2f(v.x) * inv);
    atomicAdd(&agg[(size_t)d * HDIM + 4 * q + 1], bf2f(v.y) * inv);
    atomicAdd(&agg[(size_t)d * HDIM + 4 * q + 2], bf2f(v.z) * inv);
    atomicAdd(&agg[(size_t)d * HDIM + 4 * q + 3], bf2f(v.w) * inv);
  }
}

__global__ __launch_bounds__(256) void k_fix2(const int* __restrict__ cntM,
                                              const int* __restrict__ ovfM,
                                              const unsigned short* __restrict__ xbM,
                                              const int* __restrict__ curM,
                                              float* __restrict__ aggM,
                                              const int* __restrict__ cntU,
                                              const int* __restrict__ ovfU,
                                              const unsigned short* __restrict__ xbU,
                                              const int* __restrict__ curU,
                                              float* __restrict__ aggU) {
  if (blockIdx.x < 16) fix_body(cntM, ovfM, xbM, curM, aggM, blockIdx.x, 16);
  else                 fix_body(cntU, ovfU, xbU, curU, aggU, blockIdx.x - 16, 16);
}

// ---------------- MFMA transform (r13 proven): out = [agg|X] @ [Wl;Wr] + b ----------------
template <int OUTBF>
__global__ __launch_bounds__(256) void k_xmfma(const float* A,
                                               const unsigned short* X,
                                               const float* __restrict__ Wl,
                                               const float* __restrict__ Wr,
                                               const float* __restrict__ bias,
                                               void* outv,
                                               int n_dst, int do_relu) {
  __shared__ unsigned short sWt[64][136];  // W^T bf16, padded
  __shared__ float sOut[4][16][68];        // per-wave C staging

  int t = threadIdx.x;
  for (int id = t; id < 64 * 128; id += 256) {
    int col = id & 63;
    int k = id >> 6;
    float wv = (k < 64) ? Wl[k * 64 + col] : Wr[(k - 64) * 64 + col];
    sWt[col][k] = f2bf(wv);
  }
  __syncthreads();

  int w = t >> 6;
  int l = t & 63;
  int lm = l & 15;
  int lg = l >> 4;
  int wid = blockIdx.x * 4 + w;
  int nw = gridDim.x * 4;
  int ntiles = (n_dst + 15) >> 4;

  for (int tile = wid; tile < ntiles; tile += nw) {
    int nbase = tile << 4;
    int row = nbase + lm;
    int rowc = row < n_dst ? row : (n_dst - 1);

    bf16x8 afr[4];
    const float* ar = A + (size_t)rowc * HDIM;
#pragma unroll
    for (int s = 0; s < 2; ++s) {
      float4 f0 = *(const float4*)(ar + 32 * s + 8 * lg);
      float4 f1 = *(const float4*)(ar + 32 * s + 8 * lg + 4);
      bf16x8 v;
      v[0] = (short)f2bf(f0.x); v[1] = (short)f2bf(f0.y);
      v[2] = (short)f2bf(f0.z); v[3] = (short)f2bf(f0.w);
      v[4] = (short)f2bf(f1.x); v[5] = (short)f2bf(f1.y);
      v[6] = (short)f2bf(f1.z); v[7] = (short)f2bf(f1.w);
      afr[s] = v;
    }
    const unsigned short* xr = X + (size_t)rowc * HDIM;
#pragma unroll
    for (int s = 0; s < 2; ++s) {
      afr[2 + s] = *(const bf16x8*)(xr + 32 * s + 8 * lg);
    }

    f32x4 zz = {0.f, 0.f, 0.f, 0.f};
    f32x4 acc[4];
#pragma unroll
    for (int n = 0; n < 4; ++n) acc[n] = zz;
#pragma unroll
    for (int s = 0; s < 4; ++s) {
#pragma unroll
      for (int n = 0; n < 4; ++n) {
        bf16x8 bfr = *(const bf16x8*)(&sWt[16 * n + lm][32 * s + 8 * lg]);
        acc[n] = __builtin_amdgcn_mfma_f32_16x16x32_bf16(afr[s], bfr, acc[n], 0, 0, 0);
      }
    }

#pragma unroll
    for (int n = 0; n < 4; ++n) {
      float bj = bias[16 * n + lm];
#pragma unroll
      for (int r = 0; r < 4; ++r) {
        float v = acc[n][r] + bj;
        if (do_relu) v = fmaxf(v, 0.f);
        sOut[w][lg * 4 + r][16 * n + lm] = v;
      }
    }

    int node = nbase + (l >> 2);
    if (node < n_dst) {
      int c0 = (l & 3) * 16;
      float4 o0 = *(const float4*)&sOut[w][l >> 2][c0];
      float4 o1 = *(const float4*)&sOut[w][l >> 2][c0 + 4];
      float4 o2 = *(const float4*)&sOut[w][l >> 2][c0 + 8];
      float4 o3 = *(const float4*)&sOut[w][l >> 2][c0 + 12];
      if (OUTBF) {
        unsigned short* ob = (unsigned short*)outv;
        uint4 p0, p1;
        p0.x = (unsigned int)f2bf(o0.x) | ((unsigned int)f2bf(o0.y) << 16);
        p0.y = (unsigned int)f2bf(o0.z) | ((unsigned int)f2bf(o0.w) << 16);
        p0.z = (unsigned int)f2bf(o1.x) | ((unsigned int)f2bf(o1.y) << 16);
        p0.w = (unsigned int)f2bf(o1.z) | ((unsigned int)f2bf(o1.w) << 16);
        p1.x = (unsigned int)f2bf(o2.x) | ((unsigned int)f2bf(o2.y) << 16);
        p1.y = (unsigned int)f2bf(o2.z) | ((unsigned int)f2bf(o2.w) << 16);
        p1.z = (unsigned int)f2bf(o3.x) | ((unsigned int)f2bf(o3.y) << 16);
        p1.w = (unsigned int)f2bf(o3.z) | ((unsigned int)f2bf(o3.w) << 16);
        *(uint4*)&ob[(size_t)node * HDIM + c0] = p0;
        *(uint4*)&ob[(size_t)node * HDIM + c0 + 8] = p1;
      } else {
        float* of = (float*)outv;
        *(float4*)&of[(size_t)node * HDIM + c0] = o0;
        *(float4*)&of[(size_t)node * HDIM + c0 + 4] = o1;
        *(float4*)&of[(size_t)node * HDIM + c0 + 8] = o2;
        *(float4*)&of[(size_t)node * HDIM + c0 + 12] = o3;
      }
    }
  }
}

// ---------------- launch ----------------

static inline int imin(int a, int b) { return a < b ? a : b; }

extern "C" void kernel_launch(void* const* d_in, const int* in_sizes, int n_in,
                              void* d_out, int out_size, void* d_ws, size_t ws_size,
                              hipStream_t stream) {
  const int NU = in_sizes[0];
  const int NM = in_sizes[1];
  const int E  = in_sizes[2];

  const int* src_um = (const int*)d_in[2];
  const int* dst_um = (const int*)d_in[3];
  const float* user_table  = (const float*)d_in[6];
  const float* movie_table = (const float*)d_in[7];
  const float* Wl1_um = (const float*)d_in[8];
  const float* Wr1_um = (const float*)d_in[9];
  const float* Wl1_mu = (const float*)d_in[10];
  const float* Wr1_mu = (const float*)d_in[11];
  const float* Wl2_um = (const float*)d_in[12];
  const float* Wr2_um = (const float*)d_in[13];
  const float* Wl2_mu = (const float*)d_in[14];
  const float* Wr2_mu = (const float*)d_in[15];
  const float* b1_um = (const float*)d_in[16];
  const float* b1_mu = (const float*)d_in[17];
  const float* b2_um = (const float*)d_in[18];
  const float* b2_mu = (const float*)d_in[19];

  float* out_u2 = (float*)d_out;                       // [NU,64]
  float* out_m2 = (float*)d_out + (size_t)NU * HDIM;   // [NM,64]
  float* aggu = out_u2;   // agg scratch in d_out; layer2 xform in-place per-row
  float* aggm = out_m2;
  // packed binned edge scratch lives in d_out (dead before aggs run)
  unsigned int* binnedM = (unsigned int*)d_out;        // 8 MB
  unsigned int* binnedU = (unsigned int*)d_out + E;    // +8 MB

  // workspace carve (256B aligned); total ~68 MB
  char* ws = (char*)d_ws;
  size_t off = 0;
  auto carve = [&](size_t bytes) -> char* {
    char* p = ws + off;
    off = (off + bytes + 255) & ~(size_t)255;
    return p;
  };
  int* meta = (int*)carve((size_t)(NM + NU + 2) * 4);
  int* curm = meta;
  int* curu = meta + NM;
  int* ovfm_cnt = meta + NM + NU;
  int* ovfu_cnt = meta + NM + NU + 1;
  int nmeta = NM + NU + 2;
  int* ovfm = (int*)carve((size_t)OVF_MAX * 2 * 4);
  int* ovfu = (int*)carve((size_t)OVF_MAX * 2 * 4);
  int* bktm = (int*)carve((size_t)NM * CAP_M * 4);                        // user ids (int)
  unsigned short* bktu = (unsigned short*)carve((size_t)NU * CAP_U * 2);  // movie ids (ushort)
  unsigned short* mb = (unsigned short*)carve((size_t)NM * HDIM * 2);     // bf16 movie tbl -> m1
  unsigned short* ub = (unsigned short*)carve((size_t)NU * HDIM * 2);     // bf16 user tbl -> u1
  int* ghM = (int*)carve((size_t)NBIN * NBLK * 4);   // 4MB (scanned in-place)
  int* ghU = (int*)carve((size_t)NBIN * NBLK * 4);   // 4MB (scanned in-place)
  int* part = (int*)carve(1024 * 4);
  (void)ws_size;

  const int TB = 256;
  int nscan = NBIN * NBLK;             // 1048576
  int nbscan = (nscan + 1023) / 1024;  // 1024

  // 0) init: zero counters + bf16 table copies
  int n8u = NU * HDIM / 8, n8m = NM * HDIM / 8;
  k_init<<<3072, TB, 0, stream>>>(meta, nmeta, user_table, ub, n8u,
                                  movie_table, mb, n8m);

  // 1) fused binned build: hist -> in-place scans -> packed scatter -> fillbins
  k_hist2<<<NBLK, TB, 0, stream>>>(src_um, dst_um, E, NM, NU, ghM, ghU);
  k_block_sum<<<nbscan, TB, 0, stream>>>(ghM, part, nscan);
  k_scan_part4<<<1, TB, 0, stream>>>(part, nbscan);
  k_scan_final<<<nbscan, TB, 0, stream>>>(ghM, part, ghM, nscan);
  k_block_sum<<<nbscan, TB, 0, stream>>>(ghU, part, nscan);
  k_scan_part4<<<1, TB, 0, stream>>>(part, nbscan);
  k_scan_final<<<nbscan, TB, 0, stream>>>(ghU, part, ghU, nscan);
  k_scatter2<<<NBLK, TB, 0, stream>>>(src_um, dst_um, E, NM, NU,
                                      ghM, ghU, binnedM, binnedU);
  k_fillbin<int><<<NBIN, TB, 0, stream>>>(binnedM, ghM, E, NM, CAP_M,
                                          bktm, curm, ovfm_cnt, ovfm);
  k_fillbin<unsigned short><<<NBIN, TB, 0, stream>>>(binnedU, ghU, E, NU, CAP_U,
                                                     bktu, curu, ovfu_cnt, ovfu);

  int gAm = imin((NM + 31) / 32, 8192);
  int gAu = imin((NU + 31) / 32, 8192);
  int gXm = (NM + 63) / 64;   // 64 nodes/block (4 waves x 16)
  int gXu = (NU + 63) / 64;

  // 2) layer 1 (relu): serial aggs (r9 lesson), fix, MFMA xforms (in-place bf16)
  k_agg8<int><<<gAm, TB, 0, stream>>>(ub, curm, bktm, CAP_M, aggm, NM);
  k_agg8<unsigned short><<<gAu, TB, 0, stream>>>(mb, curu, bktu, CAP_U, aggu, NU);
  k_fix2<<<32, TB, 0, stream>>>(ovfm_cnt, ovfm, ub, curm, aggm,
                                ovfu_cnt, ovfu, mb, curu, aggu);
  k_xmfma<1><<<gXm, TB, 0, stream>>>(aggm, mb, Wl1_um, Wr1_um, b1_um,
                                     mb, NM, 1);   // mb becomes m1 (bf16)
  k_xmfma<1><<<gXu, TB, 0, stream>>>(aggu, ub, Wl1_mu, Wr1_mu, b1_mu,
                                     ub, NU, 1);   // ub becomes u1 (bf16)

  // 3) layer 2 (no relu): aggs into d_out, MFMA xforms in-place -> fp32 out
  k_agg8<int><<<gAm, TB, 0, stream>>>(ub, curm, bktm, CAP_M, aggm, NM);
  k_agg8<unsigned short><<<gAu, TB, 0, stream>>>(mb, curu, bktu, CAP_U, aggu, NU);
  k_fix2<<<32, TB, 0, stream>>>(ovfm_cnt, ovfm, ub, curm, aggm,
                                ovfu_cnt, ovfu, mb, curu, aggu);
  k_xmfma<0><<<gXm, TB, 0, stream>>>(aggm, mb, Wl2_um, Wr2_um, b2_um,
                                     out_m2, NM, 0);
  k_xmfma<0><<<gXu, TB, 0, stream>>>(aggu, ub, Wl2_mu, Wr2_mu, b2_mu,
                                     out_u2, NU, 0);
}

// Round 20
// 373.342 us; speedup vs baseline: 1.0103x; 1.0103x over previous
//
#include <hip/hip_runtime.h>

#define HDIM 64
#define CAP_M 96
#define CAP_U 32
#define OVF_MAX 65536
#define NBIN 512
#define NBLK 512
#define SENT 0xFFFFFFFFu

typedef __attribute__((ext_vector_type(8))) short bf16x8;   // 8 bf16 (4 VGPRs)
typedef __attribute__((ext_vector_type(4))) float f32x4;    // 4 fp32

// ---------------- bf16 helpers ----------------
__device__ __forceinline__ float bf2f(unsigned short u) {
  unsigned int x = ((unsigned int)u) << 16;
  return __uint_as_float(x);
}
__device__ __forceinline__ unsigned short f2bf(float f) {
  unsigned int x = __float_as_uint(f);
  unsigned int r = (x + 0x7FFFu + ((x >> 16) & 1u)) >> 16;  // RNE
  return (unsigned short)r;
}
__device__ __forceinline__ int rup16(int x) { return (x + 15) & ~15; }

// bin-local base: lo(b) = ceil(b*Nd/NBIN); bin(k) = floor(k*NBIN/Nd)
__device__ __forceinline__ int bin_lo(int b, int Nd) {
  return (int)(((long long)b * Nd + NBIN - 1) >> 9);
}

// ---------------- init: zero meta + bf16 table copies (r13 proven) ----------------
__global__ __launch_bounds__(256) void k_init(int* __restrict__ meta, int nmeta,
                                              const float* __restrict__ ut,
                                              unsigned short* __restrict__ ub, int n8u,
                                              const float* __restrict__ mt,
                                              unsigned short* __restrict__ mb, int n8m) {
  int bid = blockIdx.x;
  if (bid < 512) {
    int i = bid * 256 + threadIdx.x;
    for (int j = i; j < nmeta; j += 512 * 256) meta[j] = 0;
  } else if (bid < 512 + 2048) {
    int i = (bid - 512) * 256 + threadIdx.x;
    for (int j = i; j < n8u; j += 2048 * 256) {
      const float4* p = (const float4*)(ut + (size_t)j * 8);
      float4 a = p[0], b = p[1];
      uint4 o;
      o.x = (unsigned int)f2bf(a.x) | ((unsigned int)f2bf(a.y) << 16);
      o.y = (unsigned int)f2bf(a.z) | ((unsigned int)f2bf(a.w) << 16);
      o.z = (unsigned int)f2bf(b.x) | ((unsigned int)f2bf(b.y) << 16);
      o.w = (unsigned int)f2bf(b.z) | ((unsigned int)f2bf(b.w) << 16);
      *(uint4*)(ub + (size_t)j * 8) = o;
    }
  } else {
    int i = (bid - 512 - 2048) * 256 + threadIdx.x;
    for (int j = i; j < n8m; j += 512 * 256) {
      const float4* p = (const float4*)(mt + (size_t)j * 8);
      float4 a = p[0], b = p[1];
      uint4 o;
      o.x = (unsigned int)f2bf(a.x) | ((unsigned int)f2bf(a.y) << 16);
      o.y = (unsigned int)f2bf(a.z) | ((unsigned int)f2bf(a.w) << 16);
      o.z = (unsigned int)f2bf(b.x) | ((unsigned int)f2bf(b.y) << 16);
      o.w = (unsigned int)f2bf(b.z) | ((unsigned int)f2bf(b.w) << 16);
      *(uint4*)(mb + (size_t)j * 8) = o;
    }
  }
}

// ---------------- binned CSR build (no global atomics on hot path) ----------------
// Phase 1 (fused): per-block 512-bin histograms for BOTH directions.
__global__ __launch_bounds__(256) void k_hist2(const int* __restrict__ srcU,
                                               const int* __restrict__ dstM,
                                               int E, int NMd, int NUd,
                                               int* __restrict__ ghM,
                                               int* __restrict__ ghU) {
  __shared__ int hM[NBIN];
  __shared__ int hU[NBIN];
  int t = threadIdx.x;
  hM[t] = 0; hM[t + 256] = 0;
  hU[t] = 0; hU[t + 256] = 0;
  __syncthreads();
  int e4 = (E + 3) >> 2;
  int c4 = (e4 + NBLK - 1) / NBLK;
  int clen = c4 << 2;
  int s = blockIdx.x * clen;
  int epos = s + clen; if (epos > E) epos = E;
  for (int i = s + 4 * t; i < epos; i += 1024) {
    int n = epos - i; if (n > 4) n = 4;
    if (n == 4) {
      int4 d4 = *(const int4*)&dstM[i];
      int4 s4 = *(const int4*)&srcU[i];
      atomicAdd(&hM[(int)((long long)d4.x * NBIN / NMd)], 1);
      atomicAdd(&hM[(int)((long long)d4.y * NBIN / NMd)], 1);
      atomicAdd(&hM[(int)((long long)d4.z * NBIN / NMd)], 1);
      atomicAdd(&hM[(int)((long long)d4.w * NBIN / NMd)], 1);
      atomicAdd(&hU[(int)((long long)s4.x * NBIN / NUd)], 1);
      atomicAdd(&hU[(int)((long long)s4.y * NBIN / NUd)], 1);
      atomicAdd(&hU[(int)((long long)s4.z * NBIN / NUd)], 1);
      atomicAdd(&hU[(int)((long long)s4.w * NBIN / NUd)], 1);
    } else {
      for (int j = 0; j < n; ++j) {
        atomicAdd(&hM[(int)((long long)dstM[i + j] * NBIN / NMd)], 1);
        atomicAdd(&hU[(int)((long long)srcU[i + j] * NBIN / NUd)], 1);
      }
    }
  }
  __syncthreads();
  ghM[(size_t)t * NBLK + blockIdx.x] = hM[t];
  ghM[(size_t)(t + 256) * NBLK + blockIdx.x] = hM[t + 256];
  ghU[(size_t)t * NBLK + blockIdx.x] = hU[t];
  ghU[(size_t)(t + 256) * NBLK + blockIdx.x] = hU[t + 256];
}

// scan kernels over PADDED counts (rup16 applied to input); raw gh preserved.
template <int PAD>
__global__ void k_block_sum(const int* __restrict__ in, int* __restrict__ part, int n) {
  __shared__ int s[256];
  int b = blockIdx.x, t = threadIdx.x;
  int base = b * 1024;
  int v = 0;
  for (int i = t; i < 1024; i += 256) {
    int idx = base + i;
    if (idx < n) v += PAD ? rup16(in[idx]) : in[idx];
  }
  s[t] = v;
  __syncthreads();
  for (int o = 128; o > 0; o >>= 1) {
    if (t < o) s[t] += s[t + o];
    __syncthreads();
  }
  if (t == 0) part[b] = s[0];
}

__global__ void k_scan_part(int* __restrict__ part, int nb) {
  __shared__ int s[256];
  int t = threadIdx.x;
  int v = (t < nb) ? part[t] : 0;
  s[t] = v;
  __syncthreads();
  for (int o = 1; o < 256; o <<= 1) {
    int u = (t >= o) ? s[t - o] : 0;
    __syncthreads();
    s[t] += u;
    __syncthreads();
  }
  if (t < nb) part[t] = s[t] - v;  // exclusive
}

template <int PAD>
__global__ void k_scan_final(const int* __restrict__ in, const int* __restrict__ part,
                             int* __restrict__ out, int n) {
  __shared__ int s[256];
  int b = blockIdx.x, t = threadIdx.x;
  int base = b * 1024 + t * 4;
  int a[4];
#pragma unroll
  for (int i = 0; i < 4; i++) {
    int idx = base + i;
    a[i] = (idx < n) ? (PAD ? rup16(in[idx]) : in[idx]) : 0;
  }
  int tsum = a[0] + a[1] + a[2] + a[3];
  s[t] = tsum;
  __syncthreads();
  for (int o = 1; o < 256; o <<= 1) {
    int u = (t >= o) ? s[t - o] : 0;
    __syncthreads();
    s[t] += u;
    __syncthreads();
  }
  int excl = s[t] - tsum + part[b];
#pragma unroll
  for (int i = 0; i < 4; i++) {
    if (base + i < n) out[base + i] = excl;
    excl += a[i];
  }
}

// Phase 2 (fused): scatter BOTH directions into 64B-aligned per-(bin,blk)
// segments (padded offsets) -> every binned line has exactly ONE writer
// block (r19 lesson: cross-block line sharing was the scatter bottleneck).
// Tail-pads its own segments with SENT.
__global__ __launch_bounds__(256) void k_scatter2(const int* __restrict__ srcU,
                                                  const int* __restrict__ dstM,
                                                  int E, int NMd, int NUd,
                                                  const int* __restrict__ offsM,
                                                  const int* __restrict__ offsU,
                                                  unsigned int* __restrict__ binnedM,
                                                  unsigned int* __restrict__ binnedU) {
  __shared__ int lcM[NBIN];
  __shared__ int lcU[NBIN];
  int t = threadIdx.x;
  lcM[t] = offsM[(size_t)t * NBLK + blockIdx.x];
  lcM[t + 256] = offsM[(size_t)(t + 256) * NBLK + blockIdx.x];
  lcU[t] = offsU[(size_t)t * NBLK + blockIdx.x];
  lcU[t + 256] = offsU[(size_t)(t + 256) * NBLK + blockIdx.x];
  __syncthreads();
  int e4 = (E + 3) >> 2;
  int c4 = (e4 + NBLK - 1) / NBLK;
  int clen = c4 << 2;
  int s = blockIdx.x * clen;
  int epos = s + clen; if (epos > E) epos = E;
  for (int i = s + 4 * t; i < epos; i += 1024) {
    int n = epos - i; if (n > 4) n = 4;
    if (n == 4) {
      int4 d4 = *(const int4*)&dstM[i];
      int4 s4 = *(const int4*)&srcU[i];
#pragma unroll
      for (int k = 0; k < 4; ++k) {
        int dd = (k == 0) ? d4.x : (k == 1) ? d4.y : (k == 2) ? d4.z : d4.w;
        int ss = (k == 0) ? s4.x : (k == 1) ? s4.y : (k == 2) ? s4.z : s4.w;
        int bm = (int)((long long)dd * NBIN / NMd);
        int pm = atomicAdd(&lcM[bm], 1);
        binnedM[pm] = ((unsigned int)(dd - bin_lo(bm, NMd)) << 18) | (unsigned int)ss;
        int bu = (int)((long long)ss * NBIN / NUd);
        int pu = atomicAdd(&lcU[bu], 1);
        binnedU[pu] = ((unsigned int)(ss - bin_lo(bu, NUd)) << 18) | (unsigned int)dd;
      }
    } else {
      for (int j = 0; j < n; ++j) {
        int dd = dstM[i + j], ss = srcU[i + j];
        int bm = (int)((long long)dd * NBIN / NMd);
        int pm = atomicAdd(&lcM[bm], 1);
        binnedM[pm] = ((unsigned int)(dd - bin_lo(bm, NMd)) << 18) | (unsigned int)ss;
        int bu = (int)((long long)ss * NBIN / NUd);
        int pu = atomicAdd(&lcU[bu], 1);
        binnedU[pu] = ((unsigned int)(ss - bin_lo(bu, NUd)) << 18) | (unsigned int)dd;
      }
    }
  }
  __syncthreads();
  // self-pad segment tails with SENT (same lines this block already owns)
#pragma unroll
  for (int rep = 0; rep < 2; ++rep) {
    int bin = t + rep * 256;
    int s0 = offsM[(size_t)bin * NBLK + blockIdx.x];
    int fin = lcM[bin];
    int pe = s0 + rup16(fin - s0);
    for (int i = fin; i < pe; ++i) binnedM[i] = SENT;
    s0 = offsU[(size_t)bin * NBLK + blockIdx.x];
    fin = lcU[bin];
    pe = s0 + rup16(fin - s0);
    for (int i = fin; i < pe; ++i) binnedU[i] = SENT;
  }
}

// Phase 3: one block per bin; cursors in LDS; decode packed records, skip SENT.
template <typename IT>
__global__ __launch_bounds__(256) void k_fillbin(const unsigned int* __restrict__ binned,
                                                 const int* __restrict__ offs,
                                                 const int* __restrict__ ghraw,
                                                 int E, int Nd, int cap,
                                                 IT* __restrict__ bkt,
                                                 int* __restrict__ cur,
                                                 int* __restrict__ ovf_cnt,
                                                 int* __restrict__ ovf) {
  __shared__ int lcur[400];
  int b = blockIdx.x;
  int t = threadIdx.x;
  int lo = bin_lo(b, Nd);
  int hi = bin_lo(b + 1, Nd);
  if (b == NBIN - 1) hi = Nd;
  int width = hi - lo;
  for (int i = t; i < width; i += 256) lcur[i] = 0;
  __syncthreads();
  int start = offs[(size_t)b * NBLK];
  int end;
  if (b == NBIN - 1) {
    int lastoff = offs[(size_t)NBIN * NBLK - 1];
    int lastcnt = ghraw[(size_t)NBIN * NBLK - 1];
    end = lastoff + rup16(lastcnt);
  } else {
    end = offs[(size_t)(b + 1) * NBLK];
  }
  for (int i = start + t; i < end; i += 256) {
    unsigned int p = binned[i];
    if (p == SENT) continue;
    int li = (int)(p >> 18);
    int val = (int)(p & 0x3FFFFu);
    int pos = atomicAdd(&lcur[li], 1);
    if (pos < cap) bkt[(size_t)(lo + li) * cap + pos] = (IT)val;
    else { int q = atomicAdd(ovf_cnt, 1); if (q < OVF_MAX) { ovf[2 * q] = lo + li; ovf[2 * q + 1] = val; } }
  }
  __syncthreads();
  for (int i = t; i < width; i += 256) cur[lo + i] = lcur[i];
}

// ---------------- aggregation: 8 lanes/node, 16B uint4 loads (r13 proven) ----------------
__device__ __forceinline__ void acc8(float4& a, float4& b, uint4 w) {
  a.x += __uint_as_float(w.x << 16);
  a.y += __uint_as_float(w.x & 0xFFFF0000u);
  a.z += __uint_as_float(w.y << 16);
  a.w += __uint_as_float(w.y & 0xFFFF0000u);
  b.x += __uint_as_float(w.z << 16);
  b.y += __uint_as_float(w.z & 0xFFFF0000u);
  b.z += __uint_as_float(w.w << 16);
  b.w += __uint_as_float(w.w & 0xFFFF0000u);
}

template <typename IT>
__global__ __launch_bounds__(256) void k_agg8(const unsigned short* __restrict__ xb,
                                              const int* __restrict__ cur,
                                              const IT* __restrict__ bkt,
                                              int cap,
                                              float* __restrict__ agg,
                                              int n_dst) {
  int t = threadIdx.x;
  int q = t & 7;
  int gg = (blockIdx.x * 256 + t) >> 3;
  int stride = (gridDim.x * 256) >> 3;

  for (int node = gg; node < n_dst; node += stride) {
    int deg = cur[node];
    int nb = deg < cap ? deg : cap;
    const IT* lst = bkt + (size_t)node * cap;
    float4 a = make_float4(0.f, 0.f, 0.f, 0.f);
    float4 b = a;
    int e = 0;
    for (; e + 4 <= nb; e += 4) {
      int i0, i1, i2, i3;
      if (sizeof(IT) == 2) {
        ushort4 ia = *(const ushort4*)&lst[e];
        i0 = ia.x; i1 = ia.y; i2 = ia.z; i3 = ia.w;
      } else {
        int4 ia = *(const int4*)&lst[e];
        i0 = ia.x; i1 = ia.y; i2 = ia.z; i3 = ia.w;
      }
      uint4 w0 = *(const uint4*)&xb[(size_t)i0 * HDIM + 8 * q];
      uint4 w1 = *(const uint4*)&xb[(size_t)i1 * HDIM + 8 * q];
      uint4 w2 = *(const uint4*)&xb[(size_t)i2 * HDIM + 8 * q];
      uint4 w3 = *(const uint4*)&xb[(size_t)i3 * HDIM + 8 * q];
      acc8(a, b, w0);
      acc8(a, b, w1);
      acc8(a, b, w2);
      acc8(a, b, w3);
    }
    for (; e < nb; ++e) {
      uint4 w0 = *(const uint4*)&xb[(size_t)lst[e] * HDIM + 8 * q];
      acc8(a, b, w0);
    }
    float inv = deg > 0 ? 1.f / (float)deg : 0.f;
    a.x *= inv; a.y *= inv; a.z *= inv; a.w *= inv;
    b.x *= inv; b.y *= inv; b.z *= inv; b.w *= inv;
    *(float4*)&agg[(size_t)node * HDIM + 8 * q] = a;
    *(float4*)&agg[(size_t)node * HDIM + 8 * q + 4] = b;
  }
}

// ---------------- overflow fixup (combined; normally a no-op) ----------------
__device__ __forceinline__ void fix_body(const int* __restrict__ cnt_p,
                                         const int* __restrict__ ovf,
                                         const unsigned short* __restrict__ xb,
                                         const int* __restrict__ cur,
                                         float* __restrict__ agg,
                                         int bid, int nblk) {
  int n = *cnt_p;
  if (n > OVF_MAX) n = OVF_MAX;
  int tid = bid * 256 + threadIdx.x;
  int q = tid & 15;
  int p = tid >> 4;
  int stride = (nblk * 256) >> 4;
  for (; p < n; p += stride) {
    int d = ovf[2 * p];
    int s = ovf[2 * p + 1];
    float inv = 1.f / (float)cur[d];
    ushort4 v = *(const ushort4*)&xb[(size_t)s * HDIM + 4 * q];
    atomicAdd(&agg[(size_t)d * HDIM + 4 * q + 0], bf2f(v.x) * inv);
    atomicAdd(&agg[(size_t)d * HDIM + 4 * q + 1], bf2f(v.y) * inv);
    atomicAdd(&agg[(size_t)d * HDIM + 4 * q + 2], bf2f(v.z) * inv);
    atomicAdd(&agg[(size_t)d * HDIM + 4 * q + 3], bf2f(v.w) * inv);
  }
}

__global__ __launch_bounds__(256) void k_fix2(const int* __restrict__ cntM,
                                              const int* __restrict__ ovfM,
                                              const unsigned short* __restrict__ xbM,
                                              const int* __restrict__ curM,
                                              float* __restrict__ aggM,
                                              const int* __restrict__ cntU,
                                              const int* __restrict__ ovfU,
                                              const unsigned short* __restrict__ xbU,
                                              const int* __restrict__ curU,
                                              float* __restrict__ aggU) {
  if (blockIdx.x < 16) fix_body(cntM, ovfM, xbM, curM, aggM, blockIdx.x, 16);
  else                 fix_body(cntU, ovfU, xbU, curU, aggU, blockIdx.x - 16, 16);
}

// ---------------- MFMA transform (r13 proven): out = [agg|X] @ [Wl;Wr] + b ----------------
template <int OUTBF>
__global__ __launch_bounds__(256) void k_xmfma(const float* A,
                                               const unsigned short* X,
                                               const float* __restrict__ Wl,
                                               const float* __restrict__ Wr,
                                               const float* __restrict__ bias,
                                               void* outv,
                                               int n_dst, int do_relu) {
  __shared__ unsigned short sWt[64][136];  // W^T bf16, padded
  __shared__ float sOut[4][16][68];        // per-wave C staging

  int t = threadIdx.x;
  for (int id = t; id < 64 * 128; id += 256) {
    int col = id & 63;
    int k = id >> 6;
    float wv = (k < 64) ? Wl[k * 64 + col] : Wr[(k - 64) * 64 + col];
    sWt[col][k] = f2bf(wv);
  }
  __syncthreads();

  int w = t >> 6;
  int l = t & 63;
  int lm = l & 15;
  int lg = l >> 4;
  int wid = blockIdx.x * 4 + w;
  int nw = gridDim.x * 4;
  int ntiles = (n_dst + 15) >> 4;

  for (int tile = wid; tile < ntiles; tile += nw) {
    int nbase = tile << 4;
    int row = nbase + lm;
    int rowc = row < n_dst ? row : (n_dst - 1);

    bf16x8 afr[4];
    const float* ar = A + (size_t)rowc * HDIM;
#pragma unroll
    for (int s = 0; s < 2; ++s) {
      float4 f0 = *(const float4*)(ar + 32 * s + 8 * lg);
      float4 f1 = *(const float4*)(ar + 32 * s + 8 * lg + 4);
      bf16x8 v;
      v[0] = (short)f2bf(f0.x); v[1] = (short)f2bf(f0.y);
      v[2] = (short)f2bf(f0.z); v[3] = (short)f2bf(f0.w);
      v[4] = (short)f2bf(f1.x); v[5] = (short)f2bf(f1.y);
      v[6] = (short)f2bf(f1.z); v[7] = (short)f2bf(f1.w);
      afr[s] = v;
    }
    const unsigned short* xr = X + (size_t)rowc * HDIM;
#pragma unroll
    for (int s = 0; s < 2; ++s) {
      afr[2 + s] = *(const bf16x8*)(xr + 32 * s + 8 * lg);
    }

    f32x4 zz = {0.f, 0.f, 0.f, 0.f};
    f32x4 acc[4];
#pragma unroll
    for (int n = 0; n < 4; ++n) acc[n] = zz;
#pragma unroll
    for (int s = 0; s < 4; ++s) {
#pragma unroll
      for (int n = 0; n < 4; ++n) {
        bf16x8 bfr = *(const bf16x8*)(&sWt[16 * n + lm][32 * s + 8 * lg]);
        acc[n] = __builtin_amdgcn_mfma_f32_16x16x32_bf16(afr[s], bfr, acc[n], 0, 0, 0);
      }
    }

#pragma unroll
    for (int n = 0; n < 4; ++n) {
      float bj = bias[16 * n + lm];
#pragma unroll
      for (int r = 0; r < 4; ++r) {
        float v = acc[n][r] + bj;
        if (do_relu) v = fmaxf(v, 0.f);
        sOut[w][lg * 4 + r][16 * n + lm] = v;
      }
    }

    int node = nbase + (l >> 2);
    if (node < n_dst) {
      int c0 = (l & 3) * 16;
      float4 o0 = *(const float4*)&sOut[w][l >> 2][c0];
      float4 o1 = *(const float4*)&sOut[w][l >> 2][c0 + 4];
      float4 o2 = *(const float4*)&sOut[w][l >> 2][c0 + 8];
      float4 o3 = *(const float4*)&sOut[w][l >> 2][c0 + 12];
      if (OUTBF) {
        unsigned short* ob = (unsigned short*)outv;
        uint4 p0, p1;
        p0.x = (unsigned int)f2bf(o0.x) | ((unsigned int)f2bf(o0.y) << 16);
        p0.y = (unsigned int)f2bf(o0.z) | ((unsigned int)f2bf(o0.w) << 16);
        p0.z = (unsigned int)f2bf(o1.x) | ((unsigned int)f2bf(o1.y) << 16);
        p0.w = (unsigned int)f2bf(o1.z) | ((unsigned int)f2bf(o1.w) << 16);
        p1.x = (unsigned int)f2bf(o2.x) | ((unsigned int)f2bf(o2.y) << 16);
        p1.y = (unsigned int)f2bf(o2.z) | ((unsigned int)f2bf(o2.w) << 16);
        p1.z = (unsigned int)f2bf(o3.x) | ((unsigned int)f2bf(o3.y) << 16);
        p1.w = (unsigned int)f2bf(o3.z) | ((unsigned int)f2bf(o3.w) << 16);
        *(uint4*)&ob[(size_t)node * HDIM + c0] = p0;
        *(uint4*)&ob[(size_t)node * HDIM + c0 + 8] = p1;
      } else {
        float* of = (float*)outv;
        *(float4*)&of[(size_t)node * HDIM + c0] = o0;
        *(float4*)&of[(size_t)node * HDIM + c0 + 4] = o1;
        *(float4*)&of[(size_t)node * HDIM + c0 + 8] = o2;
        *(float4*)&of[(size_t)node * HDIM + c0 + 12] = o3;
      }
    }
  }
}

// ---------------- launch ----------------

static inline int imin(int a, int b) { return a < b ? a : b; }

extern "C" void kernel_launch(void* const* d_in, const int* in_sizes, int n_in,
                              void* d_out, int out_size, void* d_ws, size_t ws_size,
                              hipStream_t stream) {
  const int NU = in_sizes[0];
  const int NM = in_sizes[1];
  const int E  = in_sizes[2];

  const int* src_um = (const int*)d_in[2];
  const int* dst_um = (const int*)d_in[3];
  const float* user_table  = (const float*)d_in[6];
  const float* movie_table = (const float*)d_in[7];
  const float* Wl1_um = (const float*)d_in[8];
  const float* Wr1_um = (const float*)d_in[9];
  const float* Wl1_mu = (const float*)d_in[10];
  const float* Wr1_mu = (const float*)d_in[11];
  const float* Wl2_um = (const float*)d_in[12];
  const float* Wr2_um = (const float*)d_in[13];
  const float* Wl2_mu = (const float*)d_in[14];
  const float* Wr2_mu = (const float*)d_in[15];
  const float* b1_um = (const float*)d_in[16];
  const float* b1_mu = (const float*)d_in[17];
  const float* b2_um = (const float*)d_in[18];
  const float* b2_mu = (const float*)d_in[19];

  float* out_u2 = (float*)d_out;                       // [NU,64]
  float* out_m2 = (float*)d_out + (size_t)NU * HDIM;   // [NM,64]
  float* aggu = out_u2;   // agg scratch in d_out; layer2 xform in-place per-row
  float* aggm = out_m2;
  // padded binned scratch in d_out (dead before aggs run); <=25MB each
  unsigned int* binnedM = (unsigned int*)d_out;               // [0, 25.2MB)
  unsigned int* binnedU = (unsigned int*)d_out + 6300000;     // [25.2, 50.4MB)

  // workspace carve (256B aligned); total ~66 MB
  char* ws = (char*)d_ws;
  size_t off = 0;
  auto carve = [&](size_t bytes) -> char* {
    char* p = ws + off;
    off = (off + bytes + 255) & ~(size_t)255;
    return p;
  };
  int* meta = (int*)carve((size_t)(NM + NU + 2) * 4);
  int* curm = meta;
  int* curu = meta + NM;
  int* ovfm_cnt = meta + NM + NU;
  int* ovfu_cnt = meta + NM + NU + 1;
  int nmeta = NM + NU + 2;
  int* ovfm = (int*)carve((size_t)OVF_MAX * 2 * 4);
  int* ovfu = (int*)carve((size_t)OVF_MAX * 2 * 4);
  int* bktm = (int*)carve((size_t)NM * CAP_M * 4);                        // user ids (int)
  unsigned short* bktu = (unsigned short*)carve((size_t)NU * CAP_U * 2);  // movie ids (ushort)
  unsigned short* mb = (unsigned short*)carve((size_t)NM * HDIM * 2);     // bf16 movie tbl -> m1
  unsigned short* ub = (unsigned short*)carve((size_t)NU * HDIM * 2);     // bf16 user tbl -> u1
  int* ghM  = (int*)carve((size_t)NBIN * NBLK * 4);   // raw counts, 1MB
  int* ghsM = (int*)carve((size_t)NBIN * NBLK * 4);   // padded offsets, 1MB
  int* ghU  = (int*)carve((size_t)NBIN * NBLK * 4);   // 1MB
  int* ghsU = (int*)carve((size_t)NBIN * NBLK * 4);   // 1MB
  int* part = (int*)carve(256 * 4);
  (void)ws_size;

  const int TB = 256;
  int nscan = NBIN * NBLK;             // 262144
  int nbscan = (nscan + 1023) / 1024;  // 256

  // 0) init: zero counters + bf16 table copies
  int n8u = NU * HDIM / 8, n8m = NM * HDIM / 8;
  k_init<<<3072, TB, 0, stream>>>(meta, nmeta, user_table, ub, n8u,
                                  movie_table, mb, n8m);

  // 1) binned build: hist -> PADDED scans -> line-exclusive scatter -> fillbins
  k_hist2<<<NBLK, TB, 0, stream>>>(src_um, dst_um, E, NM, NU, ghM, ghU);
  k_block_sum<1><<<nbscan, TB, 0, stream>>>(ghM, part, nscan);
  k_scan_part<<<1, TB, 0, stream>>>(part, nbscan);
  k_scan_final<1><<<nbscan, TB, 0, stream>>>(ghM, part, ghsM, nscan);
  k_block_sum<1><<<nbscan, TB, 0, stream>>>(ghU, part, nscan);
  k_scan_part<<<1, TB, 0, stream>>>(part, nbscan);
  k_scan_final<1><<<nbscan, TB, 0, stream>>>(ghU, part, ghsU, nscan);
  k_scatter2<<<NBLK, TB, 0, stream>>>(src_um, dst_um, E, NM, NU,
                                      ghsM, ghsU, binnedM, binnedU);
  k_fillbin<int><<<NBIN, TB, 0, stream>>>(binnedM, ghsM, ghM, E, NM, CAP_M,
                                          bktm, curm, ovfm_cnt, ovfm);
  k_fillbin<unsigned short><<<NBIN, TB, 0, stream>>>(binnedU, ghsU, ghU, E, NU, CAP_U,
                                                     bktu, curu, ovfu_cnt, ovfu);

  int gAm = imin((NM + 31) / 32, 8192);
  int gAu = imin((NU + 31) / 32, 8192);
  int gXm = (NM + 63) / 64;   // 64 nodes/block (4 waves x 16)
  int gXu = (NU + 63) / 64;

  // 2) layer 1 (relu): serial aggs (r9 lesson), fix, MFMA xforms (in-place bf16)
  k_agg8<int><<<gAm, TB, 0, stream>>>(ub, curm, bktm, CAP_M, aggm, NM);
  k_agg8<unsigned short><<<gAu, TB, 0, stream>>>(mb, curu, bktu, CAP_U, aggu, NU);
  k_fix2<<<32, TB, 0, stream>>>(ovfm_cnt, ovfm, ub, curm, aggm,
                                ovfu_cnt, ovfu, mb, curu, aggu);
  k_xmfma<1><<<gXm, TB, 0, stream>>>(aggm, mb, Wl1_um, Wr1_um, b1_um,
                                     mb, NM, 1);   // mb becomes m1 (bf16)
  k_xmfma<1><<<gXu, TB, 0, stream>>>(aggu, ub, Wl1_mu, Wr1_mu, b1_mu,
                                     ub, NU, 1);   // ub becomes u1 (bf16)

  // 3) layer 2 (no relu): aggs into d_out, MFMA xforms in-place -> fp32 out
  k_agg8<int><<<gAm, TB, 0, stream>>>(ub, curm, bktm, CAP_M, aggm, NM);
  k_agg8<unsigned short><<<gAu, TB, 0, stream>>>(mb, curu, bktu, CAP_U, aggu, NU);
  k_fix2<<<32, TB, 0, stream>>>(ovfm_cnt, ovfm, ub, curm, aggm,
                                ovfu_cnt, ovfu, mb, curu, aggu);
  k_xmfma<0><<<gXm, TB, 0, stream>>>(aggm, mb, Wl2_um, Wr2_um, b2_um,
                                     out_m2, NM, 0);
  k_xmfma<0><<<gXu, TB, 0, stream>>>(aggu, ub, Wl2_mu, Wr2_mu, b2_mu,
                                     out_u2, NU, 0);
}

// Round 21
// 344.143 us; speedup vs baseline: 1.0960x; 1.0848x over previous
//
#include <hip/hip_runtime.h>

#define HDIM 64
#define CAP_M 96
#define CAP_U 32
#define OVF_MAX 65536
#define NBIN 512
#define NBLK 512

typedef __attribute__((ext_vector_type(8))) short bf16x8;   // 8 bf16 (4 VGPRs)
typedef __attribute__((ext_vector_type(4))) float f32x4;    // 4 fp32

// ---------------- bf16 helpers ----------------
__device__ __forceinline__ float bf2f(unsigned short u) {
  unsigned int x = ((unsigned int)u) << 16;
  return __uint_as_float(x);
}
__device__ __forceinline__ unsigned short f2bf(float f) {
  unsigned int x = __float_as_uint(f);
  unsigned int r = (x + 0x7FFFu + ((x >> 16) & 1u)) >> 16;  // RNE
  return (unsigned short)r;
}

// ---------------- init: zero meta + bf16 table copies (r13 proven) ----------------
__global__ __launch_bounds__(256) void k_init(int* __restrict__ meta, int nmeta,
                                              const float* __restrict__ ut,
                                              unsigned short* __restrict__ ub, int n8u,
                                              const float* __restrict__ mt,
                                              unsigned short* __restrict__ mb, int n8m) {
  int bid = blockIdx.x;
  if (bid < 512) {
    int i = bid * 256 + threadIdx.x;
    for (int j = i; j < nmeta; j += 512 * 256) meta[j] = 0;
  } else if (bid < 512 + 2048) {
    int i = (bid - 512) * 256 + threadIdx.x;
    for (int j = i; j < n8u; j += 2048 * 256) {
      const float4* p = (const float4*)(ut + (size_t)j * 8);
      float4 a = p[0], b = p[1];
      uint4 o;
      o.x = (unsigned int)f2bf(a.x) | ((unsigned int)f2bf(a.y) << 16);
      o.y = (unsigned int)f2bf(a.z) | ((unsigned int)f2bf(a.w) << 16);
      o.z = (unsigned int)f2bf(b.x) | ((unsigned int)f2bf(b.y) << 16);
      o.w = (unsigned int)f2bf(b.z) | ((unsigned int)f2bf(b.w) << 16);
      *(uint4*)(ub + (size_t)j * 8) = o;
    }
  } else {
    int i = (bid - 512 - 2048) * 256 + threadIdx.x;
    for (int j = i; j < n8m; j += 512 * 256) {
      const float4* p = (const float4*)(mt + (size_t)j * 8);
      float4 a = p[0], b = p[1];
      uint4 o;
      o.x = (unsigned int)f2bf(a.x) | ((unsigned int)f2bf(a.y) << 16);
      o.y = (unsigned int)f2bf(a.z) | ((unsigned int)f2bf(a.w) << 16);
      o.z = (unsigned int)f2bf(b.x) | ((unsigned int)f2bf(b.y) << 16);
      o.w = (unsigned int)f2bf(b.z) | ((unsigned int)f2bf(b.w) << 16);
      *(uint4*)(mb + (size_t)j * 8) = o;
    }
  }
}

// ---------------- binned CSR build (no global atomics on hot path) ----------------
// Phase 1 (fused): per-block 512-bin histograms for BOTH directions.
__global__ __launch_bounds__(256) void k_hist2(const int* __restrict__ srcU,
                                               const int* __restrict__ dstM,
                                               int E, int NMd, int NUd,
                                               int* __restrict__ ghM,
                                               int* __restrict__ ghU) {
  __shared__ int hM[NBIN];
  __shared__ int hU[NBIN];
  int t = threadIdx.x;
  hM[t] = 0; hM[t + 256] = 0;
  hU[t] = 0; hU[t + 256] = 0;
  __syncthreads();
  int e4 = (E + 3) >> 2;
  int c4 = (e4 + NBLK - 1) / NBLK;
  int clen = c4 << 2;
  int s = blockIdx.x * clen;
  int epos = s + clen; if (epos > E) epos = E;
  for (int i = s + 4 * t; i < epos; i += 1024) {
    int n = epos - i; if (n > 4) n = 4;
    if (n == 4) {
      int4 d4 = *(const int4*)&dstM[i];
      int4 s4 = *(const int4*)&srcU[i];
      atomicAdd(&hM[(int)((long long)d4.x * NBIN / NMd)], 1);
      atomicAdd(&hM[(int)((long long)d4.y * NBIN / NMd)], 1);
      atomicAdd(&hM[(int)((long long)d4.z * NBIN / NMd)], 1);
      atomicAdd(&hM[(int)((long long)d4.w * NBIN / NMd)], 1);
      atomicAdd(&hU[(int)((long long)s4.x * NBIN / NUd)], 1);
      atomicAdd(&hU[(int)((long long)s4.y * NBIN / NUd)], 1);
      atomicAdd(&hU[(int)((long long)s4.z * NBIN / NUd)], 1);
      atomicAdd(&hU[(int)((long long)s4.w * NBIN / NUd)], 1);
    } else {
      for (int j = 0; j < n; ++j) {
        atomicAdd(&hM[(int)((long long)dstM[i + j] * NBIN / NMd)], 1);
        atomicAdd(&hU[(int)((long long)srcU[i + j] * NBIN / NUd)], 1);
      }
    }
  }
  __syncthreads();
  ghM[(size_t)t * NBLK + blockIdx.x] = hM[t];
  ghM[(size_t)(t + 256) * NBLK + blockIdx.x] = hM[t + 256];
  ghU[(size_t)t * NBLK + blockIdx.x] = hU[t];
  ghU[(size_t)(t + 256) * NBLK + blockIdx.x] = hU[t + 256];
}

// ---- fused scan chain: both directions in each dispatch ----
// blocks [0,256): ghM chunks -> part[0..256); [256,512): ghU -> part[256..512)
__global__ void k_block_sum2(const int* __restrict__ ghM, const int* __restrict__ ghU,
                             int* __restrict__ part, int n) {
  __shared__ int s[256];
  int b = blockIdx.x, t = threadIdx.x;
  const int* in = (b < 256) ? ghM : ghU;
  int cb = (b < 256) ? b : (b - 256);
  int base = cb * 1024;
  int v = 0;
  for (int i = t; i < 1024; i += 256) {
    int idx = base + i;
    if (idx < n) v += in[idx];
  }
  s[t] = v;
  __syncthreads();
  for (int o = 128; o > 0; o >>= 1) {
    if (t < o) s[t] += s[t + o];
    __syncthreads();
  }
  if (t == 0) part[b] = s[0];
}

// one block: exclusive-scan part[0..256) then part[256..512)
__global__ void k_scan_part2(int* __restrict__ part) {
  __shared__ int s[256];
  int t = threadIdx.x;
#pragma unroll
  for (int half = 0; half < 2; ++half) {
    int v = part[half * 256 + t];
    s[t] = v;
    __syncthreads();
    for (int o = 1; o < 256; o <<= 1) {
      int u = (t >= o) ? s[t - o] : 0;
      __syncthreads();
      s[t] += u;
      __syncthreads();
    }
    part[half * 256 + t] = s[t] - v;  // exclusive
    __syncthreads();
  }
}

// blocks [0,256): ghM -> ghsM; [256,512): ghU -> ghsU
__global__ void k_scan_final2(const int* __restrict__ ghM, const int* __restrict__ ghU,
                              const int* __restrict__ part,
                              int* __restrict__ ghsM, int* __restrict__ ghsU, int n) {
  __shared__ int s[256];
  int b = blockIdx.x, t = threadIdx.x;
  const int* in = (b < 256) ? ghM : ghU;
  int* out = (b < 256) ? ghsM : ghsU;
  int cb = (b < 256) ? b : (b - 256);
  int base = cb * 1024 + t * 4;
  int a[4];
#pragma unroll
  for (int i = 0; i < 4; i++) a[i] = (base + i < n) ? in[base + i] : 0;
  int tsum = a[0] + a[1] + a[2] + a[3];
  s[t] = tsum;
  __syncthreads();
  for (int o = 1; o < 256; o <<= 1) {
    int u = (t >= o) ? s[t - o] : 0;
    __syncthreads();
    s[t] += u;
    __syncthreads();
  }
  int excl = s[t] - tsum + part[b];
#pragma unroll
  for (int i = 0; i < 4; i++) {
    if (base + i < n) out[base + i] = excl;
    excl += a[i];
  }
}

// Phase 2 (fused): scatter BOTH directions in one edge pass (int2 records,
// r17 best-measured form; r18 pack / r19 occupancy / r20 pad all refuted).
__global__ __launch_bounds__(256) void k_scatter2(const int* __restrict__ srcU,
                                                  const int* __restrict__ dstM,
                                                  int E, int NMd, int NUd,
                                                  const int* __restrict__ offsM,
                                                  const int* __restrict__ offsU,
                                                  int2* __restrict__ binnedM,
                                                  int2* __restrict__ binnedU) {
  __shared__ int lcM[NBIN];
  __shared__ int lcU[NBIN];
  int t = threadIdx.x;
  lcM[t] = offsM[(size_t)t * NBLK + blockIdx.x];
  lcM[t + 256] = offsM[(size_t)(t + 256) * NBLK + blockIdx.x];
  lcU[t] = offsU[(size_t)t * NBLK + blockIdx.x];
  lcU[t + 256] = offsU[(size_t)(t + 256) * NBLK + blockIdx.x];
  __syncthreads();
  int e4 = (E + 3) >> 2;
  int c4 = (e4 + NBLK - 1) / NBLK;
  int clen = c4 << 2;
  int s = blockIdx.x * clen;
  int epos = s + clen; if (epos > E) epos = E;
  for (int i = s + 4 * t; i < epos; i += 1024) {
    int n = epos - i; if (n > 4) n = 4;
    if (n == 4) {
      int4 d4 = *(const int4*)&dstM[i];
      int4 s4 = *(const int4*)&srcU[i];
#pragma unroll
      for (int k = 0; k < 4; ++k) {
        int dd = (k == 0) ? d4.x : (k == 1) ? d4.y : (k == 2) ? d4.z : d4.w;
        int ss = (k == 0) ? s4.x : (k == 1) ? s4.y : (k == 2) ? s4.z : s4.w;
        int bm = (int)((long long)dd * NBIN / NMd);
        int pm = atomicAdd(&lcM[bm], 1);
        binnedM[pm] = make_int2(dd, ss);
        int bu = (int)((long long)ss * NBIN / NUd);
        int pu = atomicAdd(&lcU[bu], 1);
        binnedU[pu] = make_int2(ss, dd);
      }
    } else {
      for (int j = 0; j < n; ++j) {
        int dd = dstM[i + j], ss = srcU[i + j];
        int bm = (int)((long long)dd * NBIN / NMd);
        int pm = atomicAdd(&lcM[bm], 1);
        binnedM[pm] = make_int2(dd, ss);
        int bu = (int)((long long)ss * NBIN / NUd);
        int pu = atomicAdd(&lcU[bu], 1);
        binnedU[pu] = make_int2(ss, dd);
      }
    }
  }
}

// Phase 3 (fused): blocks [0,NBIN) -> M side, [NBIN,2*NBIN) -> U side.
template <typename IT>
__device__ __forceinline__ void fillbin_body(const int2* __restrict__ binned,
                                             const int* __restrict__ offs,
                                             int b, int E, int Nd, int cap,
                                             IT* __restrict__ bkt,
                                             int* __restrict__ cur,
                                             int* __restrict__ ovf_cnt,
                                             int* __restrict__ ovf,
                                             int* lcur) {
  int t = threadIdx.x;
  int lo = (int)(((long long)b * Nd + NBIN - 1) >> 9);
  int hi = (int)(((long long)(b + 1) * Nd + NBIN - 1) >> 9);
  if (b == NBIN - 1) hi = Nd;
  int width = hi - lo;
  for (int i = t; i < width; i += 256) lcur[i] = 0;
  __syncthreads();
  int start = offs[(size_t)b * NBLK];
  int end = (b == NBIN - 1) ? E : offs[(size_t)(b + 1) * NBLK];
  for (int i = start + t; i < end; i += 256) {
    int2 p = binned[i];
    int li = p.x - lo;
    int pos = atomicAdd(&lcur[li], 1);
    if (pos < cap) bkt[(size_t)p.x * cap + pos] = (IT)p.y;
    else { int q = atomicAdd(ovf_cnt, 1); if (q < OVF_MAX) { ovf[2 * q] = p.x; ovf[2 * q + 1] = p.y; } }
  }
  __syncthreads();
  for (int i = t; i < width; i += 256) cur[lo + i] = lcur[i];
}

__global__ __launch_bounds__(256) void k_fillbin2(const int2* __restrict__ binnedM,
                                                  const int* __restrict__ offsM,
                                                  int NMd, int* __restrict__ bktM,
                                                  int* __restrict__ curM,
                                                  int* __restrict__ ovfM_cnt,
                                                  int* __restrict__ ovfM,
                                                  const int2* __restrict__ binnedU,
                                                  const int* __restrict__ offsU,
                                                  int NUd, unsigned short* __restrict__ bktU,
                                                  int* __restrict__ curU,
                                                  int* __restrict__ ovfU_cnt,
                                                  int* __restrict__ ovfU,
                                                  int E) {
  __shared__ int lcur[400];
  int b = blockIdx.x;
  if (b < NBIN)
    fillbin_body<int>(binnedM, offsM, b, E, NMd, CAP_M, bktM, curM, ovfM_cnt, ovfM, lcur);
  else
    fillbin_body<unsigned short>(binnedU, offsU, b - NBIN, E, NUd, CAP_U,
                                 bktU, curU, ovfU_cnt, ovfU, lcur);
}

// ---------------- aggregation: 8 lanes/node, 16B uint4 loads (r13 proven) ----------------
__device__ __forceinline__ void acc8(float4& a, float4& b, uint4 w) {
  a.x += __uint_as_float(w.x << 16);
  a.y += __uint_as_float(w.x & 0xFFFF0000u);
  a.z += __uint_as_float(w.y << 16);
  a.w += __uint_as_float(w.y & 0xFFFF0000u);
  b.x += __uint_as_float(w.z << 16);
  b.y += __uint_as_float(w.z & 0xFFFF0000u);
  b.z += __uint_as_float(w.w << 16);
  b.w += __uint_as_float(w.w & 0xFFFF0000u);
}

template <typename IT>
__global__ __launch_bounds__(256) void k_agg8(const unsigned short* __restrict__ xb,
                                              const int* __restrict__ cur,
                                              const IT* __restrict__ bkt,
                                              int cap,
                                              float* __restrict__ agg,
                                              int n_dst) {
  int t = threadIdx.x;
  int q = t & 7;
  int gg = (blockIdx.x * 256 + t) >> 3;
  int stride = (gridDim.x * 256) >> 3;

  for (int node = gg; node < n_dst; node += stride) {
    int deg = cur[node];
    int nb = deg < cap ? deg : cap;
    const IT* lst = bkt + (size_t)node * cap;
    float4 a = make_float4(0.f, 0.f, 0.f, 0.f);
    float4 b = a;
    int e = 0;
    for (; e + 4 <= nb; e += 4) {
      int i0, i1, i2, i3;
      if (sizeof(IT) == 2) {
        ushort4 ia = *(const ushort4*)&lst[e];
        i0 = ia.x; i1 = ia.y; i2 = ia.z; i3 = ia.w;
      } else {
        int4 ia = *(const int4*)&lst[e];
        i0 = ia.x; i1 = ia.y; i2 = ia.z; i3 = ia.w;
      }
      uint4 w0 = *(const uint4*)&xb[(size_t)i0 * HDIM + 8 * q];
      uint4 w1 = *(const uint4*)&xb[(size_t)i1 * HDIM + 8 * q];
      uint4 w2 = *(const uint4*)&xb[(size_t)i2 * HDIM + 8 * q];
      uint4 w3 = *(const uint4*)&xb[(size_t)i3 * HDIM + 8 * q];
      acc8(a, b, w0);
      acc8(a, b, w1);
      acc8(a, b, w2);
      acc8(a, b, w3);
    }
    for (; e < nb; ++e) {
      uint4 w0 = *(const uint4*)&xb[(size_t)lst[e] * HDIM + 8 * q];
      acc8(a, b, w0);
    }
    float inv = deg > 0 ? 1.f / (float)deg : 0.f;
    a.x *= inv; a.y *= inv; a.z *= inv; a.w *= inv;
    b.x *= inv; b.y *= inv; b.z *= inv; b.w *= inv;
    *(float4*)&agg[(size_t)node * HDIM + 8 * q] = a;
    *(float4*)&agg[(size_t)node * HDIM + 8 * q + 4] = b;
  }
}

// ---------------- overflow fixup (combined; normally a no-op) ----------------
__device__ __forceinline__ void fix_body(const int* __restrict__ cnt_p,
                                         const int* __restrict__ ovf,
                                         const unsigned short* __restrict__ xb,
                                         const int* __restrict__ cur,
                                         float* __restrict__ agg,
                                         int bid, int nblk) {
  int n = *cnt_p;
  if (n > OVF_MAX) n = OVF_MAX;
  int tid = bid * 256 + threadIdx.x;
  int q = tid & 15;
  int p = tid >> 4;
  int stride = (nblk * 256) >> 4;
  for (; p < n; p += stride) {
    int d = ovf[2 * p];
    int s = ovf[2 * p + 1];
    float inv = 1.f / (float)cur[d];
    ushort4 v = *(const ushort4*)&xb[(size_t)s * HDIM + 4 * q];
    atomicAdd(&agg[(size_t)d * HDIM + 4 * q + 0], bf2f(v.x) * inv);
    atomicAdd(&agg[(size_t)d * HDIM + 4 * q + 1], bf2f(v.y) * inv);
    atomicAdd(&agg[(size_t)d * HDIM + 4 * q + 2], bf2f(v.z) * inv);
    atomicAdd(&agg[(size_t)d * HDIM + 4 * q + 3], bf2f(v.w) * inv);
  }
}

__global__ __launch_bounds__(256) void k_fix2(const int* __restrict__ cntM,
                                              const int* __restrict__ ovfM,
                                              const unsigned short* __restrict__ xbM,
                                              const int* __restrict__ curM,
                                              float* __restrict__ aggM,
                                              const int* __restrict__ cntU,
                                              const int* __restrict__ ovfU,
                                              const unsigned short* __restrict__ xbU,
                                              const int* __restrict__ curU,
                                              float* __restrict__ aggU) {
  if (blockIdx.x < 16) fix_body(cntM, ovfM, xbM, curM, aggM, blockIdx.x, 16);
  else                 fix_body(cntU, ovfU, xbU, curU, aggU, blockIdx.x - 16, 16);
}

// ---------------- MFMA transform (r13 proven): out = [agg|X] @ [Wl;Wr] + b ----------------
template <int OUTBF>
__global__ __launch_bounds__(256) void k_xmfma(const float* A,
                                               const unsigned short* X,
                                               const float* __restrict__ Wl,
                                               const float* __restrict__ Wr,
                                               const float* __restrict__ bias,
                                               void* outv,
                                               int n_dst, int do_relu) {
  __shared__ unsigned short sWt[64][136];  // W^T bf16, padded
  __shared__ float sOut[4][16][68];        // per-wave C staging

  int t = threadIdx.x;
  for (int id = t; id < 64 * 128; id += 256) {
    int col = id & 63;
    int k = id >> 6;
    float wv = (k < 64) ? Wl[k * 64 + col] : Wr[(k - 64) * 64 + col];
    sWt[col][k] = f2bf(wv);
  }
  __syncthreads();

  int w = t >> 6;
  int l = t & 63;
  int lm = l & 15;
  int lg = l >> 4;
  int wid = blockIdx.x * 4 + w;
  int nw = gridDim.x * 4;
  int ntiles = (n_dst + 15) >> 4;

  for (int tile = wid; tile < ntiles; tile += nw) {
    int nbase = tile << 4;
    int row = nbase + lm;
    int rowc = row < n_dst ? row : (n_dst - 1);

    bf16x8 afr[4];
    const float* ar = A + (size_t)rowc * HDIM;
#pragma unroll
    for (int s = 0; s < 2; ++s) {
      float4 f0 = *(const float4*)(ar + 32 * s + 8 * lg);
      float4 f1 = *(const float4*)(ar + 32 * s + 8 * lg + 4);
      bf16x8 v;
      v[0] = (short)f2bf(f0.x); v[1] = (short)f2bf(f0.y);
      v[2] = (short)f2bf(f0.z); v[3] = (short)f2bf(f0.w);
      v[4] = (short)f2bf(f1.x); v[5] = (short)f2bf(f1.y);
      v[6] = (short)f2bf(f1.z); v[7] = (short)f2bf(f1.w);
      afr[s] = v;
    }
    const unsigned short* xr = X + (size_t)rowc * HDIM;
#pragma unroll
    for (int s = 0; s < 2; ++s) {
      afr[2 + s] = *(const bf16x8*)(xr + 32 * s + 8 * lg);
    }

    f32x4 zz = {0.f, 0.f, 0.f, 0.f};
    f32x4 acc[4];
#pragma unroll
    for (int n = 0; n < 4; ++n) acc[n] = zz;
#pragma unroll
    for (int s = 0; s < 4; ++s) {
#pragma unroll
      for (int n = 0; n < 4; ++n) {
        bf16x8 bfr = *(const bf16x8*)(&sWt[16 * n + lm][32 * s + 8 * lg]);
        acc[n] = __builtin_amdgcn_mfma_f32_16x16x32_bf16(afr[s], bfr, acc[n], 0, 0, 0);
      }
    }

#pragma unroll
    for (int n = 0; n < 4; ++n) {
      float bj = bias[16 * n + lm];
#pragma unroll
      for (int r = 0; r < 4; ++r) {
        float v = acc[n][r] + bj;
        if (do_relu) v = fmaxf(v, 0.f);
        sOut[w][lg * 4 + r][16 * n + lm] = v;
      }
    }

    int node = nbase + (l >> 2);
    if (node < n_dst) {
      int c0 = (l & 3) * 16;
      float4 o0 = *(const float4*)&sOut[w][l >> 2][c0];
      float4 o1 = *(const float4*)&sOut[w][l >> 2][c0 + 4];
      float4 o2 = *(const float4*)&sOut[w][l >> 2][c0 + 8];
      float4 o3 = *(const float4*)&sOut[w][l >> 2][c0 + 12];
      if (OUTBF) {
        unsigned short* ob = (unsigned short*)outv;
        uint4 p0, p1;
        p0.x = (unsigned int)f2bf(o0.x) | ((unsigned int)f2bf(o0.y) << 16);
        p0.y = (unsigned int)f2bf(o0.z) | ((unsigned int)f2bf(o0.w) << 16);
        p0.z = (unsigned int)f2bf(o1.x) | ((unsigned int)f2bf(o1.y) << 16);
        p0.w = (unsigned int)f2bf(o1.z) | ((unsigned int)f2bf(o1.w) << 16);
        p1.x = (unsigned int)f2bf(o2.x) | ((unsigned int)f2bf(o2.y) << 16);
        p1.y = (unsigned int)f2bf(o2.z) | ((unsigned int)f2bf(o2.w) << 16);
        p1.z = (unsigned int)f2bf(o3.x) | ((unsigned int)f2bf(o3.y) << 16);
        p1.w = (unsigned int)f2bf(o3.z) | ((unsigned int)f2bf(o3.w) << 16);
        *(uint4*)&ob[(size_t)node * HDIM + c0] = p0;
        *(uint4*)&ob[(size_t)node * HDIM + c0 + 8] = p1;
      } else {
        float* of = (float*)outv;
        *(float4*)&of[(size_t)node * HDIM + c0] = o0;
        *(float4*)&of[(size_t)node * HDIM + c0 + 4] = o1;
        *(float4*)&of[(size_t)node * HDIM + c0 + 8] = o2;
        *(float4*)&of[(size_t)node * HDIM + c0 + 12] = o3;
      }
    }
  }
}

// ---------------- launch ----------------

static inline int imin(int a, int b) { return a < b ? a : b; }

extern "C" void kernel_launch(void* const* d_in, const int* in_sizes, int n_in,
                              void* d_out, int out_size, void* d_ws, size_t ws_size,
                              hipStream_t stream) {
  const int NU = in_sizes[0];
  const int NM = in_sizes[1];
  const int E  = in_sizes[2];

  const int* src_um = (const int*)d_in[2];
  const int* dst_um = (const int*)d_in[3];
  const float* user_table  = (const float*)d_in[6];
  const float* movie_table = (const float*)d_in[7];
  const float* Wl1_um = (const float*)d_in[8];
  const float* Wr1_um = (const float*)d_in[9];
  const float* Wl1_mu = (const float*)d_in[10];
  const float* Wr1_mu = (const float*)d_in[11];
  const float* Wl2_um = (const float*)d_in[12];
  const float* Wr2_um = (const float*)d_in[13];
  const float* Wl2_mu = (const float*)d_in[14];
  const float* Wr2_mu = (const float*)d_in[15];
  const float* b1_um = (const float*)d_in[16];
  const float* b1_mu = (const float*)d_in[17];
  const float* b2_um = (const float*)d_in[18];
  const float* b2_mu = (const float*)d_in[19];

  float* out_u2 = (float*)d_out;                       // [NU,64]
  float* out_m2 = (float*)d_out + (size_t)NU * HDIM;   // [NM,64]
  float* aggu = out_u2;   // agg scratch in d_out; layer2 xform in-place per-row
  float* aggm = out_m2;
  // binned edge scratch in d_out (dead before aggs run)
  int2* binnedM = (int2*)d_out;          // 16 MB
  int2* binnedU = (int2*)d_out + E;      // +16 MB (32 MB < 61 MB d_out)

  // workspace carve (256B aligned); total ~65 MB
  char* ws = (char*)d_ws;
  size_t off = 0;
  auto carve = [&](size_t bytes) -> char* {
    char* p = ws + off;
    off = (off + bytes + 255) & ~(size_t)255;
    return p;
  };
  int* meta = (int*)carve((size_t)(NM + NU + 2) * 4);
  int* curm = meta;
  int* curu = meta + NM;
  int* ovfm_cnt = meta + NM + NU;
  int* ovfu_cnt = meta + NM + NU + 1;
  int nmeta = NM + NU + 2;
  int* ovfm = (int*)carve((size_t)OVF_MAX * 2 * 4);
  int* ovfu = (int*)carve((size_t)OVF_MAX * 2 * 4);
  int* bktm = (int*)carve((size_t)NM * CAP_M * 4);                        // user ids (int)
  unsigned short* bktu = (unsigned short*)carve((size_t)NU * CAP_U * 2);  // movie ids (ushort)
  unsigned short* mb = (unsigned short*)carve((size_t)NM * HDIM * 2);     // bf16 movie tbl -> m1
  unsigned short* ub = (unsigned short*)carve((size_t)NU * HDIM * 2);     // bf16 user tbl -> u1
  int* ghM  = (int*)carve((size_t)NBIN * NBLK * 4);   // 1MB
  int* ghsM = (int*)carve((size_t)NBIN * NBLK * 4);   // 1MB
  int* ghU  = (int*)carve((size_t)NBIN * NBLK * 4);   // 1MB
  int* ghsU = (int*)carve((size_t)NBIN * NBLK * 4);   // 1MB
  int* part = (int*)carve(512 * 4);
  (void)ws_size;

  const int TB = 256;
  int nscan = NBIN * NBLK;             // 262144

  // 0) init: zero counters + bf16 table copies
  int n8u = NU * HDIM / 8, n8m = NM * HDIM / 8;
  k_init<<<3072, TB, 0, stream>>>(meta, nmeta, user_table, ub, n8u,
                                  movie_table, mb, n8m);

  // 1) binned build: hist -> fused scans -> scatter -> fused fillbin (6 dispatches)
  k_hist2<<<NBLK, TB, 0, stream>>>(src_um, dst_um, E, NM, NU, ghM, ghU);
  k_block_sum2<<<512, TB, 0, stream>>>(ghM, ghU, part, nscan);
  k_scan_part2<<<1, TB, 0, stream>>>(part);
  k_scan_final2<<<512, TB, 0, stream>>>(ghM, ghU, part, ghsM, ghsU, nscan);
  k_scatter2<<<NBLK, TB, 0, stream>>>(src_um, dst_um, E, NM, NU,
                                      ghsM, ghsU, binnedM, binnedU);
  k_fillbin2<<<2 * NBIN, TB, 0, stream>>>(binnedM, ghsM, NM, bktm, curm, ovfm_cnt, ovfm,
                                          binnedU, ghsU, NU, bktu, curu, ovfu_cnt, ovfu, E);

  int gAm = imin((NM + 31) / 32, 8192);
  int gAu = imin((NU + 31) / 32, 8192);
  int gXm = (NM + 63) / 64;   // 64 nodes/block (4 waves x 16)
  int gXu = (NU + 63) / 64;

  // 2) layer 1 (relu): serial aggs (r9 lesson), fix, MFMA xforms (in-place bf16)
  k_agg8<int><<<gAm, TB, 0, stream>>>(ub, curm, bktm, CAP_M, aggm, NM);
  k_agg8<unsigned short><<<gAu, TB, 0, stream>>>(mb, curu, bktu, CAP_U, aggu, NU);
  k_fix2<<<32, TB, 0, stream>>>(ovfm_cnt, ovfm, ub, curm, aggm,
                                ovfu_cnt, ovfu, mb, curu, aggu);
  k_xmfma<1><<<gXm, TB, 0, stream>>>(aggm, mb, Wl1_um, Wr1_um, b1_um,
                                     mb, NM, 1);   // mb becomes m1 (bf16)
  k_xmfma<1><<<gXu, TB, 0, stream>>>(aggu, ub, Wl1_mu, Wr1_mu, b1_mu,
                                     ub, NU, 1);   // ub becomes u1 (bf16)

  // 3) layer 2 (no relu): aggs into d_out, MFMA xforms in-place -> fp32 out
  k_agg8<int><<<gAm, TB, 0, stream>>>(ub, curm, bktm, CAP_M, aggm, NM);
  k_agg8<unsigned short><<<gAu, TB, 0, stream>>>(mb, curu, bktu, CAP_U, aggu, NU);
  k_fix2<<<32, TB, 0, stream>>>(ovfm_cnt, ovfm, ub, curm, aggm,
                                ovfu_cnt, ovfu, mb, curu, aggu);
  k_xmfma<0><<<gXm, TB, 0, stream>>>(aggm, mb, Wl2_um, Wr2_um, b2_um,
                                     out_m2, NM, 0);
  k_xmfma<0><<<gXu, TB, 0, stream>>>(aggu, ub, Wl2_mu, Wr2_mu, b2_mu,
                                     out_u2, NU, 0);
}